// Round 3
// baseline (552.065 us; speedup 1.0000x reference)
//
#include <hip/hip_runtime.h>

// Problem constants (fixed shapes from reference setup_inputs)
#define N_INST 32768
#define DIM    2048
#define DP     512
#define NCLS   4

typedef _Float16 half8_t __attribute__((ext_vector_type(8)));
typedef float    float4_t __attribute__((ext_vector_type(4)));

// Workspace layout (bytes). Total ~4.3 MB (Vhi eliminated this round).
#define OFF_UHI   0ull                              // DP*DIM fp16 = 2 MB
#define OFF_S     (OFF_UHI  + (size_t)DP*DIM*2)     // N fp32 = 128 KB
#define OFF_STAT  (OFF_S    + (size_t)N_INST*4)     // 2 fp32 (padded)
#define OFF_PART  (OFF_STAT + 256ull)               // 256*DIM fp32 = 2 MB
#define OFF_T     (OFF_PART + 256ull*DIM*4)         // DIM fp32 = 8 KB

#define GLOAD_LDS16(g, l) __builtin_amdgcn_global_load_lds( \
    (__attribute__((address_space(1))) void*)(g),           \
    (__attribute__((address_space(3))) void*)(l), 16, 0, 0)

__device__ __forceinline__ float tanh_fast(float x) {
  // tanh(x) = 1 - 2/(exp(2x)+1); exp overflow->inf gives exact +/-1 limits
  float e = __expf(2.0f * x);
  return 1.0f - 2.0f / (e + 1.0f);
}

// ---- fp32 -> fp16 convert (U only now; 8 elems/thread) ----
__global__ __launch_bounds__(256) void k_cvt(const float4* __restrict__ in,
                                             half8_t* __restrict__ out) {
  int i = blockIdx.x * 256 + threadIdx.x;
  float4 a = in[2 * i], b = in[2 * i + 1];
  half8_t h;
  h[0] = (_Float16)a.x; h[1] = (_Float16)a.y;
  h[2] = (_Float16)a.z; h[3] = (_Float16)a.w;
  h[4] = (_Float16)b.x; h[5] = (_Float16)b.y;
  h[6] = (_Float16)b.z; h[7] = (_Float16)b.w;
  out[i] = h;
}

// ---- fused score GEMM, fp32 V read directly:
// s[n] = sum_j Wmta[j]*tanh( Uhi[j,:] . V[n,:] )
// 128x128 block tile, BK=32, 4 waves (2x2), wave tile 64x64 = 4x4 MFMA 16x16x32.
// A (U) staged fp16 as before. B (V) staged fp32 with XOR granule swizzle:
// 16B granule g (4 floats, k=g*4..g*4+3) of tile-row r lives at LDS slot
// r*8 + (g ^ (r&7)); fragment reads then spread across all 8 bank groups
// (BW-floor 8 phases instead of 16-way conflicts with the naive layout).
__global__ __launch_bounds__(256) void k_score_gemm(
    const _Float16* __restrict__ Uhi, const float* __restrict__ V,
    const float* __restrict__ Wmta, float* __restrict__ s) {
  __shared__ _Float16 lA[128 * 32];   // 8 KB
  __shared__ float    lB[128 * 32];   // 16 KB

  const int tid = threadIdx.x;
  const int lane = tid & 63;
  const int wv = tid >> 6;        // 0..3
  const int waveM = wv >> 1;      // 0..1
  const int waveN = wv & 1;       // 0..1
  const int quad = lane >> 4;     // 0..3
  const int col = lane & 15;
  // mb fast so the 4 M-blocks sharing a V-tile are temporally adjacent (L2 reuse)
  const int mb = blockIdx.x & 3;   // 512/128
  const int nb = blockIdx.x >> 2;  // 32768/128

  const int aRow0 = mb * 128;
  const int bRow0 = nb * 128;

  float4_t acc[4][4];
  const float4_t z4 = {0.f, 0.f, 0.f, 0.f};
  for (int i = 0; i < 4; i++)
    for (int j = 0; j < 4; j++) acc[i][j] = z4;

  // precomputed per-thread staging coords
  const int aR = tid >> 2;            // A: 4 granules/row (64 B rows)
  const int aC = (tid & 3) << 3;      // halves offset
  const int bR = tid >> 3;            // B: 8 granules/row (128 B rows)
  const int bG0 = tid & 7;

  for (int k0 = 0; k0 < DIM; k0 += 32) {
    // A: 128x32 fp16 = 8 KB, 2 issues
    for (int it = 0; it < 2; ++it) {
      const int r = it * 64 + aR;
      GLOAD_LDS16(Uhi + (size_t)(aRow0 + r) * DIM + k0 + aC,
                  &lA[(it * 256 + (wv << 6)) << 3]);
    }
    // B: 128x32 fp32 = 16 KB, 4 issues, swizzled granule placement
    for (int it = 0; it < 4; ++it) {
      const int r = it * 32 + bR;
      const int g = bG0 ^ (r & 7);
      GLOAD_LDS16(V + (size_t)(bRow0 + r) * DIM + k0 + (g << 2),
                  &lB[(it * 256 + (wv << 6)) << 2]);
    }
    __syncthreads();

    half8_t af[4], bf[4];
    for (int mi = 0; mi < 4; mi++) {
      const int row = waveM * 64 + mi * 16 + col;
      af[mi] = *(const half8_t*)&lA[row * 32 + quad * 8];
    }
    for (int ni = 0; ni < 4; ni++) {
      const int row = waveN * 64 + ni * 16 + col;
      const int ga = (2 * quad) ^ (row & 7);
      const int gb = (2 * quad + 1) ^ (row & 7);
      float4_t xa = *(const float4_t*)&lB[row * 32 + ga * 4];
      float4_t xb = *(const float4_t*)&lB[row * 32 + gb * 4];
      half8_t b;
      b[0] = (_Float16)xa[0]; b[1] = (_Float16)xa[1];
      b[2] = (_Float16)xa[2]; b[3] = (_Float16)xa[3];
      b[4] = (_Float16)xb[0]; b[5] = (_Float16)xb[1];
      b[6] = (_Float16)xb[2]; b[7] = (_Float16)xb[3];
      bf[ni] = b;
    }
    for (int mi = 0; mi < 4; mi++)
      for (int ni = 0; ni < 4; ni++)
        acc[mi][ni] = __builtin_amdgcn_mfma_f32_16x16x32_f16(af[mi], bf[ni], acc[mi][ni], 0, 0, 0);
    __syncthreads();
  }

  // epilogue: C/D layout col=lane&15 (n), row=quad*4+reg (j).
  // reduce over j within block, one atomicAdd per (n, block). 8 adders/address.
  for (int ni = 0; ni < 4; ni++) {
    float v = 0.0f;
    for (int mi = 0; mi < 4; mi++) {
      const int jb = aRow0 + waveM * 64 + mi * 16 + quad * 4;
      union { float4_t v4; float f[4]; } u;
      u.v4 = acc[mi][ni];
      for (int r = 0; r < 4; r++)
        v += Wmta[jb + r] * tanh_fast(u.f[r]);
    }
    v += __shfl_xor(v, 16);
    v += __shfl_xor(v, 32);
    if (quad == 0) {
      const int n = bRow0 + waveN * 64 + ni * 16 + col;
      atomicAdd(&s[n], v);
    }
  }
}

// ---- softmax stats over s[0..N): one-pass online max+sum ----
__global__ __launch_bounds__(1024) void k_stats(const float* __restrict__ s,
                                                float* __restrict__ stats) {
  const int tid = threadIdx.x;
  const int lane = tid & 63;
  const int wvi = tid >> 6;
  __shared__ float smM[16], smP[16];
  const float4* s4 = (const float4*)s;

  float m = -3.4e38f, p = 0.0f;
  for (int i = tid; i < N_INST / 4; i += 1024) {
    float4 v = s4[i];
    float xs[4] = {v.x, v.y, v.z, v.w};
#pragma unroll
    for (int j = 0; j < 4; ++j) {
      float x = xs[j];
      float nm = fmaxf(m, x);
      p = p * __expf(m - nm) + __expf(x - nm);
      m = nm;
    }
  }
  for (int o = 32; o > 0; o >>= 1) {
    float om = __shfl_xor(m, o);
    float op = __shfl_xor(p, o);
    float nm = fmaxf(m, om);
    p = p * __expf(m - nm) + op * __expf(om - nm);
    m = nm;
  }
  if (lane == 0) { smM[wvi] = m; smP[wvi] = p; }
  __syncthreads();
  if (tid == 0) {
    float gm = smM[0];
    for (int w = 1; w < 16; w++) gm = fmaxf(gm, smM[w]);
    float sum = 0.0f;
    for (int w = 0; w < 16; w++) sum += smP[w] * __expf(smM[w] - gm);
    stats[0] = gm;
    stats[1] = 1.0f / sum;
  }
}

// ---- pooling partials from fp32 V: part[b][d] = sum_{n in blk} w[n]*V[n,d] ----
__global__ __launch_bounds__(256) void k_pool(const float* __restrict__ V,
                                              const float* __restrict__ s,
                                              const float* __restrict__ stats,
                                              float* __restrict__ part) {
  const int tid = threadIdx.x;
  const float mx = stats[0], inv = stats[1];
  const int n0 = blockIdx.x * 128;
  float acc[8] = {0.f, 0.f, 0.f, 0.f, 0.f, 0.f, 0.f, 0.f};
  for (int r = 0; r < 128; ++r) {
    const int n = n0 + r;
    const float w = __expf(s[n] - mx) * inv;
    if (w > 1e-12f) {  // block-uniform branch; skipped terms contribute < 1e-6
      const float4* vp = (const float4*)&V[(size_t)n * DIM + tid * 8];
      float4 va = vp[0], vb = vp[1];
      acc[0] += w * va.x; acc[1] += w * va.y; acc[2] += w * va.z; acc[3] += w * va.w;
      acc[4] += w * vb.x; acc[5] += w * vb.y; acc[6] += w * vb.z; acc[7] += w * vb.w;
    }
  }
  float* dst = &part[(size_t)blockIdx.x * DIM + tid * 8];
  *(float4*)(dst + 0) = make_float4(acc[0], acc[1], acc[2], acc[3]);
  *(float4*)(dst + 4) = make_float4(acc[4], acc[5], acc[6], acc[7]);
}

// ---- reduce partials: t[d] = sum_b part[b][d]; 2 MB, L2-resident ----
__global__ __launch_bounds__(256) void k_reduce(const float* __restrict__ part,
                                                float* __restrict__ t) {
  const int d = blockIdx.x * 256 + threadIdx.x;
  float acc = 0.f;
  for (int b = 0; b < 256; ++b) acc += part[(size_t)b * DIM + d];
  t[d] = acc;
}

// ---- final: l[c] = W[c,:] . t ----
__global__ __launch_bounds__(256) void k_final(const float* __restrict__ W,
                                               const float* __restrict__ t,
                                               float* __restrict__ out) {
  const int wvi = threadIdx.x >> 6;  // class id, 4 waves
  const int lane = threadIdx.x & 63;
  float p = 0.0f;
  for (int d = lane; d < DIM; d += 64) p += W[wvi * DIM + d] * t[d];
  for (int o = 32; o > 0; o >>= 1) p += __shfl_xor(p, o);
  if (lane == 0) out[wvi] = p;
}

extern "C" void kernel_launch(void* const* d_in, const int* in_sizes, int n_in,
                              void* d_out, int out_size, void* d_ws, size_t ws_size,
                              hipStream_t stream) {
  const float* Vp   = (const float*)d_in[0];  // [N, 2048]
  const float* Ut   = (const float*)d_in[1];  // [512, 2048]
  const float* Wmta = (const float*)d_in[2];  // [1, 512]
  const float* W    = (const float*)d_in[3];  // [4, 2048]
  float* out = (float*)d_out;

  char* ws = (char*)d_ws;
  _Float16* Uhi  = (_Float16*)(ws + OFF_UHI);
  float*    sBuf = (float*)(ws + OFF_S);
  float*    stat = (float*)(ws + OFF_STAT);
  float*    partB= (float*)(ws + OFF_PART);
  float*    tBuf = (float*)(ws + OFF_T);

  hipMemsetAsync(sBuf, 0, (size_t)N_INST * 4, stream);

  k_cvt<<<(DP * DIM / 8) / 256, 256, 0, stream>>>((const float4*)Ut, (half8_t*)Uhi);
  k_score_gemm<<<(DP / 128) * (N_INST / 128), 256, 0, stream>>>(Uhi, Vp, Wmta, sBuf);
  k_stats<<<1, 1024, 0, stream>>>(sBuf, stat);
  k_pool<<<N_INST / 128, 256, 0, stream>>>(Vp, sBuf, stat, partB);
  k_reduce<<<DIM / 256, 256, 0, stream>>>(partB, tBuf);
  k_final<<<1, 256, 0, stream>>>(W, tBuf, out);
}

// Round 4
// 498.355 us; speedup vs baseline: 1.1078x; 1.1078x over previous
//
#include <hip/hip_runtime.h>

// Problem constants (fixed shapes from reference setup_inputs)
#define N_INST 32768
#define DIM    2048
#define DP     512
#define NCLS   4

typedef _Float16 half8_t __attribute__((ext_vector_type(8)));
typedef float    float4_t __attribute__((ext_vector_type(4)));

// Workspace layout (bytes). Total ~4.3 MB.
#define OFF_UHI   0ull                              // DP*DIM fp16 = 2 MB
#define OFF_S     (OFF_UHI  + (size_t)DP*DIM*2)     // N fp32 = 128 KB
#define OFF_STAT  (OFF_S    + (size_t)N_INST*4)     // 2 fp32 (padded)
#define OFF_PART  (OFF_STAT + 256ull)               // 256*DIM fp32 = 2 MB

__device__ __forceinline__ float tanh_fast(float x) {
  // tanh(x) = 1 - 2/(exp(2x)+1); exp overflow->inf gives exact +/-1 limits
  float e = __expf(2.0f * x);
  return 1.0f - 2.0f / (e + 1.0f);
}

// ---- fp32 -> fp16 convert (U only; 8 elems/thread) ----
__global__ __launch_bounds__(256) void k_cvt(const float4* __restrict__ in,
                                             half8_t* __restrict__ out) {
  int i = blockIdx.x * 256 + threadIdx.x;
  float4 a = in[2 * i], b = in[2 * i + 1];
  half8_t h;
  h[0] = (_Float16)a.x; h[1] = (_Float16)a.y;
  h[2] = (_Float16)a.z; h[3] = (_Float16)a.w;
  h[4] = (_Float16)b.x; h[5] = (_Float16)b.y;
  h[6] = (_Float16)b.z; h[7] = (_Float16)b.w;
  out[i] = h;
}

// ---- fused score GEMM with register-prefetch staging:
// s[n] = sum_j Wmta[j]*tanh( Uhi[j,:] . V[n,:] )
// 128x128 tile, BK=32, 4 waves (2x2), wave tile 64x64 = 4x4 MFMA 16x16x32 f16.
// K-loop per iter: barrier1 (drains prefetch loads, latency hidden behind the
// previous iter's MFMA phase) -> ds_write staged regs (B cvt'd fp32->fp16
// here, off the MFMA dependency path) -> barrier2 (lgkm only, no vmem
// outstanding) -> issue next-tile buffer_loads -> frag reads -> 16 MFMAs.
__global__ __launch_bounds__(256) void k_score_gemm(
    const _Float16* __restrict__ Uhi, const float* __restrict__ V,
    const float* __restrict__ Wmta, float* __restrict__ s) {
  __shared__ _Float16 lA[128 * 32];   // 8 KB
  __shared__ _Float16 lB[128 * 32];   // 8 KB

  const int tid = threadIdx.x;
  const int lane = tid & 63;
  const int wv = tid >> 6;        // 0..3
  const int waveM = wv >> 1;      // 0..1
  const int waveN = wv & 1;       // 0..1
  const int quad = lane >> 4;     // 0..3
  const int col = lane & 15;

  // XCD-aware swizzle: the 4 mb-siblings of one nb sit 8 apart in blockIdx
  // (same XCD under %8 round-robin) and within a 32-block dispatch window,
  // so a V tile is fetched ~once into one XCD's L2.
  const int b = blockIdx.x;
  const int grp = b >> 5;             // nb/8 group
  const int win = b & 31;
  const int mb = win >> 3;            // 0..3
  const int nb = grp * 8 + (win & 7); // 0..255

  const int aRow0 = mb * 128;
  const int bRow0 = nb * 128;

  float4_t acc[4][4];
  const float4_t z4 = {0.f, 0.f, 0.f, 0.f};
  for (int i = 0; i < 4; i++)
    for (int j = 0; j < 4; j++) acc[i][j] = z4;

  // staging coords: 4 lanes/row, 8 elems each; two row-halves (r, r+64)
  const int stR = tid >> 2;           // 0..63
  const int stQ = (tid & 3) << 3;     // elem offset 0,8,16,24

  const _Float16* gA0 = Uhi + (size_t)(aRow0 + stR) * DIM + stQ;
  const _Float16* gA1 = Uhi + (size_t)(aRow0 + 64 + stR) * DIM + stQ;
  const float*    gB0 = V   + (size_t)(bRow0 + stR) * DIM + stQ;
  const float*    gB1 = V   + (size_t)(bRow0 + 64 + stR) * DIM + stQ;

  uint4  ra0, ra1;                 // A fp16, 16 B each
  float4 rb0a, rb0b, rb1a, rb1b;   // B fp32, 32 B per row-half

  // prefetch tile k0=0
  ra0 = *(const uint4*)(gA0);  ra1 = *(const uint4*)(gA1);
  rb0a = *(const float4*)(gB0);     rb0b = *(const float4*)(gB0 + 4);
  rb1a = *(const float4*)(gB1);     rb1b = *(const float4*)(gB1 + 4);

  for (int k0 = 0; k0 < DIM; k0 += 32) {
    __syncthreads();   // frag reads of previous iter done; drains prefetch
    // commit staged regs to LDS (B: cvt fp32->fp16 RNE)
    *(uint4*)&lA[stR * 32 + stQ] = ra0;
    *(uint4*)&lA[(stR + 64) * 32 + stQ] = ra1;
    {
      half8_t h0, h1;
      h0[0] = (_Float16)rb0a.x; h0[1] = (_Float16)rb0a.y;
      h0[2] = (_Float16)rb0a.z; h0[3] = (_Float16)rb0a.w;
      h0[4] = (_Float16)rb0b.x; h0[5] = (_Float16)rb0b.y;
      h0[6] = (_Float16)rb0b.z; h0[7] = (_Float16)rb0b.w;
      h1[0] = (_Float16)rb1a.x; h1[1] = (_Float16)rb1a.y;
      h1[2] = (_Float16)rb1a.z; h1[3] = (_Float16)rb1a.w;
      h1[4] = (_Float16)rb1b.x; h1[5] = (_Float16)rb1b.y;
      h1[6] = (_Float16)rb1b.z; h1[7] = (_Float16)rb1b.w;
      *(half8_t*)&lB[stR * 32 + stQ] = h0;
      *(half8_t*)&lB[(stR + 64) * 32 + stQ] = h1;
    }
    __syncthreads();   // ds_writes visible; no vmem outstanding here

    // issue next-tile loads NOW — latency covered by frag reads + MFMAs
    const int kp = (k0 + 32 < DIM) ? (k0 + 32) : k0;
    ra0 = *(const uint4*)(gA0 + kp);  ra1 = *(const uint4*)(gA1 + kp);
    rb0a = *(const float4*)(gB0 + kp);     rb0b = *(const float4*)(gB0 + kp + 4);
    rb1a = *(const float4*)(gB1 + kp);     rb1b = *(const float4*)(gB1 + kp + 4);

    half8_t af[4], bf[4];
    for (int mi = 0; mi < 4; mi++) {
      const int row = waveM * 64 + mi * 16 + col;
      af[mi] = *(const half8_t*)&lA[row * 32 + quad * 8];
    }
    for (int ni = 0; ni < 4; ni++) {
      const int row = waveN * 64 + ni * 16 + col;
      bf[ni] = *(const half8_t*)&lB[row * 32 + quad * 8];
    }
    for (int mi = 0; mi < 4; mi++)
      for (int ni = 0; ni < 4; ni++)
        acc[mi][ni] = __builtin_amdgcn_mfma_f32_16x16x32_f16(af[mi], bf[ni], acc[mi][ni], 0, 0, 0);
  }

  // epilogue: C/D layout col=lane&15 (n), row=quad*4+reg (j).
  // reduce over j within block, one atomicAdd per (n, block). 8 adders/address.
  for (int ni = 0; ni < 4; ni++) {
    float v = 0.0f;
    for (int mi = 0; mi < 4; mi++) {
      const int jb = aRow0 + waveM * 64 + mi * 16 + quad * 4;
      union { float4_t v4; float f[4]; } u;
      u.v4 = acc[mi][ni];
      for (int r = 0; r < 4; r++)
        v += Wmta[jb + r] * tanh_fast(u.f[r]);
    }
    v += __shfl_xor(v, 16);
    v += __shfl_xor(v, 32);
    if (quad == 0) {
      const int n = bRow0 + waveN * 64 + ni * 16 + col;
      atomicAdd(&s[n], v);
    }
  }
}

// ---- softmax stats over s[0..N): one-pass online max+sum ----
__global__ __launch_bounds__(1024) void k_stats(const float* __restrict__ s,
                                                float* __restrict__ stats) {
  const int tid = threadIdx.x;
  const int lane = tid & 63;
  const int wvi = tid >> 6;
  __shared__ float smM[16], smP[16];
  const float4* s4 = (const float4*)s;

  float m = -3.4e38f, p = 0.0f;
  for (int i = tid; i < N_INST / 4; i += 1024) {
    float4 v = s4[i];
    float xs[4] = {v.x, v.y, v.z, v.w};
#pragma unroll
    for (int j = 0; j < 4; ++j) {
      float x = xs[j];
      float nm = fmaxf(m, x);
      p = p * __expf(m - nm) + __expf(x - nm);
      m = nm;
    }
  }
  for (int o = 32; o > 0; o >>= 1) {
    float om = __shfl_xor(m, o);
    float op = __shfl_xor(p, o);
    float nm = fmaxf(m, om);
    p = p * __expf(m - nm) + op * __expf(om - nm);
    m = nm;
  }
  if (lane == 0) { smM[wvi] = m; smP[wvi] = p; }
  __syncthreads();
  if (tid == 0) {
    float gm = smM[0];
    for (int w = 1; w < 16; w++) gm = fmaxf(gm, smM[w]);
    float sum = 0.0f;
    for (int w = 0; w < 16; w++) sum += smP[w] * __expf(smM[w] - gm);
    stats[0] = gm;
    stats[1] = 1.0f / sum;
  }
}

// ---- pooling partials from fp32 V: part[b][d] = sum_{n in blk} w[n]*V[n,d]
// softmax is near-one-hot: w<1e-12 rows are skipped (block-uniform branch).
__global__ __launch_bounds__(256) void k_pool(const float* __restrict__ V,
                                              const float* __restrict__ s,
                                              const float* __restrict__ stats,
                                              float* __restrict__ part) {
  const int tid = threadIdx.x;
  const float mx = stats[0], inv = stats[1];
  const int n0 = blockIdx.x * 128;
  float acc[8] = {0.f, 0.f, 0.f, 0.f, 0.f, 0.f, 0.f, 0.f};
  for (int r = 0; r < 128; ++r) {
    const int n = n0 + r;
    const float w = __expf(s[n] - mx) * inv;
    if (w > 1e-12f) {  // skipped terms contribute < 1.6e-7 total
      const float4* vp = (const float4*)&V[(size_t)n * DIM + tid * 8];
      float4 va = vp[0], vb = vp[1];
      acc[0] += w * va.x; acc[1] += w * va.y; acc[2] += w * va.z; acc[3] += w * va.w;
      acc[4] += w * vb.x; acc[5] += w * vb.y; acc[6] += w * vb.z; acc[7] += w * vb.w;
    }
  }
  float* dst = &part[(size_t)blockIdx.x * DIM + tid * 8];
  *(float4*)(dst + 0) = make_float4(acc[0], acc[1], acc[2], acc[3]);
  *(float4*)(dst + 4) = make_float4(acc[4], acc[5], acc[6], acc[7]);
}

// ---- reduce partials + final linear fused:
// t[d] = sum_b part[b][d]; out[c] += W[c,d]*t[d] (atomic across 8 blocks)
__global__ __launch_bounds__(256) void k_reduce_final(const float* __restrict__ part,
                                                      const float* __restrict__ W,
                                                      float* __restrict__ out) {
  const int d = blockIdx.x * 256 + threadIdx.x;
  float t = 0.f;
  for (int bb = 0; bb < 256; ++bb) t += part[(size_t)bb * DIM + d];

  float pc[NCLS];
#pragma unroll
  for (int c = 0; c < NCLS; ++c) pc[c] = W[(size_t)c * DIM + d] * t;

  __shared__ float sred[4][NCLS];
  const int lane = threadIdx.x & 63;
  const int wvi = threadIdx.x >> 6;
#pragma unroll
  for (int c = 0; c < NCLS; ++c)
    for (int o = 32; o > 0; o >>= 1) pc[c] += __shfl_xor(pc[c], o);
  if (lane == 0)
    for (int c = 0; c < NCLS; ++c) sred[wvi][c] = pc[c];
  __syncthreads();
  if (threadIdx.x < NCLS) {
    float v = sred[0][threadIdx.x] + sred[1][threadIdx.x] +
              sred[2][threadIdx.x] + sred[3][threadIdx.x];
    atomicAdd(&out[threadIdx.x], v);
  }
}

extern "C" void kernel_launch(void* const* d_in, const int* in_sizes, int n_in,
                              void* d_out, int out_size, void* d_ws, size_t ws_size,
                              hipStream_t stream) {
  const float* Vp   = (const float*)d_in[0];  // [N, 2048]
  const float* Ut   = (const float*)d_in[1];  // [512, 2048]
  const float* Wmta = (const float*)d_in[2];  // [1, 512]
  const float* W    = (const float*)d_in[3];  // [4, 2048]
  float* out = (float*)d_out;

  char* ws = (char*)d_ws;
  _Float16* Uhi  = (_Float16*)(ws + OFF_UHI);
  float*    sBuf = (float*)(ws + OFF_S);
  float*    stat = (float*)(ws + OFF_STAT);
  float*    partB= (float*)(ws + OFF_PART);

  hipMemsetAsync(sBuf, 0, (size_t)N_INST * 4, stream);
  hipMemsetAsync(out, 0, (size_t)NCLS * 4, stream);

  k_cvt<<<(DP * DIM / 8) / 256, 256, 0, stream>>>((const float4*)Ut, (half8_t*)Uhi);
  k_score_gemm<<<(DP / 128) * (N_INST / 128), 256, 0, stream>>>(Uhi, Vp, Wmta, sBuf);
  k_stats<<<1, 1024, 0, stream>>>(sBuf, stat);
  k_pool<<<N_INST / 128, 256, 0, stream>>>(Vp, sBuf, stat, partB);
  k_reduce_final<<<DIM / 256, 256, 0, stream>>>(partB, W, out);
}

// Round 5
// 490.356 us; speedup vs baseline: 1.1258x; 1.0163x over previous
//
#include <hip/hip_runtime.h>

// Problem constants (fixed shapes from reference setup_inputs)
#define N_INST 32768
#define DIM    2048
#define DP     512
#define NCLS   4

typedef _Float16 half8_t __attribute__((ext_vector_type(8)));
typedef float    float4_t __attribute__((ext_vector_type(4)));

// Workspace layout (bytes). Total ~4.3 MB.
#define OFF_UHI   0ull                              // DP*DIM fp16 = 2 MB
#define OFF_S     (OFF_UHI  + (size_t)DP*DIM*2)     // N fp32 = 128 KB
#define OFF_STAT  (OFF_S    + (size_t)N_INST*4)     // 2 fp32
#define OFF_PSTAT (OFF_STAT + 256ull)               // 32*2 fp32 partial stats
#define OFF_PART  (OFF_PSTAT+ 256ull)               // 256*DIM fp32 = 2 MB

__device__ __forceinline__ float tanh_fast(float x) {
  // tanh(x) = 1 - 2/(exp(2x)+1); exp overflow->inf gives exact +/-1 limits
  float e = __expf(2.0f * x);
  return 1.0f - 2.0f / (e + 1.0f);
}

// ---- fp32 -> fp16 convert (U only; 8 elems/thread) ----
__global__ __launch_bounds__(256) void k_cvt(const float4* __restrict__ in,
                                             half8_t* __restrict__ out) {
  int i = blockIdx.x * 256 + threadIdx.x;
  float4 a = in[2 * i], b = in[2 * i + 1];
  half8_t h;
  h[0] = (_Float16)a.x; h[1] = (_Float16)a.y;
  h[2] = (_Float16)a.z; h[3] = (_Float16)a.w;
  h[4] = (_Float16)b.x; h[5] = (_Float16)b.y;
  h[6] = (_Float16)b.z; h[7] = (_Float16)b.w;
  out[i] = h;
}

// ---- fused score GEMM with register-prefetch staging + K-phase stagger:
// s[n] = sum_j Wmta[j]*tanh( Uhi[j,:] . V[n,:] )
// 128x128 tile, BK=32, 4 waves (2x2), wave tile 64x64 = 4x4 MFMA 16x16x32 f16.
// K-stagger: block's K iteration starts at (nb&63)*32 and wraps. With only 4
// distinct A-strips (M=512), un-staggered blocks hammer the same 8KB of U
// through the same few L2 banks in lock-step; stagger spreads A-requests over
// the whole 2MB U and decorrelates barrier arrivals. mb-siblings (same nb)
// stay in phase so the XCD swizzle's B-tile L2 sharing is preserved.
__global__ __launch_bounds__(256) void k_score_gemm(
    const _Float16* __restrict__ Uhi, const float* __restrict__ V,
    const float* __restrict__ Wmta, float* __restrict__ s) {
  __shared__ _Float16 lA[128 * 32];   // 8 KB
  __shared__ _Float16 lB[128 * 32];   // 8 KB

  const int tid = threadIdx.x;
  const int lane = tid & 63;
  const int wv = tid >> 6;        // 0..3
  const int waveM = wv >> 1;      // 0..1
  const int waveN = wv & 1;       // 0..1
  const int quad = lane >> 4;     // 0..3
  const int col = lane & 15;

  // XCD-aware swizzle: 4 mb-siblings of one nb sit 8 apart in blockIdx
  // (same XCD under %8 round-robin), so a V tile is fetched ~once per XCD.
  const int b = blockIdx.x;
  const int grp = b >> 5;             // nb/8 group
  const int win = b & 31;
  const int mb = win >> 3;            // 0..3
  const int nb = grp * 8 + (win & 7); // 0..255

  const int aRow0 = mb * 128;
  const int bRow0 = nb * 128;
  const int kStart = (nb & 63) << 5;  // K-phase stagger

  float4_t acc[4][4];
  const float4_t z4 = {0.f, 0.f, 0.f, 0.f};
  for (int i = 0; i < 4; i++)
    for (int j = 0; j < 4; j++) acc[i][j] = z4;

  // staging coords: 4 lanes/row, 8 elems each; two row-halves (r, r+64)
  const int stR = tid >> 2;           // 0..63
  const int stQ = (tid & 3) << 3;     // elem offset 0,8,16,24

  const _Float16* gA0 = Uhi + (size_t)(aRow0 + stR) * DIM + stQ;
  const _Float16* gA1 = Uhi + (size_t)(aRow0 + 64 + stR) * DIM + stQ;
  const float*    gB0 = V   + (size_t)(bRow0 + stR) * DIM + stQ;
  const float*    gB1 = V   + (size_t)(bRow0 + 64 + stR) * DIM + stQ;

  uint4  ra0, ra1;                 // A fp16, 16 B each
  float4 rb0a, rb0b, rb1a, rb1b;   // B fp32, 32 B per row-half

  // prefetch first tile (k = kStart)
  ra0 = *(const uint4*)(gA0 + kStart);  ra1 = *(const uint4*)(gA1 + kStart);
  rb0a = *(const float4*)(gB0 + kStart);  rb0b = *(const float4*)(gB0 + kStart + 4);
  rb1a = *(const float4*)(gB1 + kStart);  rb1b = *(const float4*)(gB1 + kStart + 4);

  for (int ki = 0; ki < 64; ++ki) {
    __syncthreads();   // frag reads of previous iter done; drains prefetch
    // commit staged regs to LDS (B: cvt fp32->fp16 RNE)
    *(uint4*)&lA[stR * 32 + stQ] = ra0;
    *(uint4*)&lA[(stR + 64) * 32 + stQ] = ra1;
    {
      half8_t h0, h1;
      h0[0] = (_Float16)rb0a.x; h0[1] = (_Float16)rb0a.y;
      h0[2] = (_Float16)rb0a.z; h0[3] = (_Float16)rb0a.w;
      h0[4] = (_Float16)rb0b.x; h0[5] = (_Float16)rb0b.y;
      h0[6] = (_Float16)rb0b.z; h0[7] = (_Float16)rb0b.w;
      h1[0] = (_Float16)rb1a.x; h1[1] = (_Float16)rb1a.y;
      h1[2] = (_Float16)rb1a.z; h1[3] = (_Float16)rb1a.w;
      h1[4] = (_Float16)rb1b.x; h1[5] = (_Float16)rb1b.y;
      h1[6] = (_Float16)rb1b.z; h1[7] = (_Float16)rb1b.w;
      *(half8_t*)&lB[stR * 32 + stQ] = h0;
      *(half8_t*)&lB[(stR + 64) * 32 + stQ] = h1;
    }
    __syncthreads();   // ds_writes visible; no vmem outstanding here

    // issue next-tile loads NOW — latency covered by frag reads + MFMAs.
    // Wraps at DIM; last iteration harmlessly re-prefetches kStart.
    const int kp = (kStart + (ki + 1) * 32) & (DIM - 1);
    ra0 = *(const uint4*)(gA0 + kp);  ra1 = *(const uint4*)(gA1 + kp);
    rb0a = *(const float4*)(gB0 + kp);  rb0b = *(const float4*)(gB0 + kp + 4);
    rb1a = *(const float4*)(gB1 + kp);  rb1b = *(const float4*)(gB1 + kp + 4);

    half8_t af[4], bf[4];
    for (int mi = 0; mi < 4; mi++) {
      const int row = waveM * 64 + mi * 16 + col;
      af[mi] = *(const half8_t*)&lA[row * 32 + quad * 8];
    }
    for (int ni = 0; ni < 4; ni++) {
      const int row = waveN * 64 + ni * 16 + col;
      bf[ni] = *(const half8_t*)&lB[row * 32 + quad * 8];
    }
    for (int mi = 0; mi < 4; mi++)
      for (int ni = 0; ni < 4; ni++)
        acc[mi][ni] = __builtin_amdgcn_mfma_f32_16x16x32_f16(af[mi], bf[ni], acc[mi][ni], 0, 0, 0);
  }

  // epilogue: C/D layout col=lane&15 (n), row=quad*4+reg (j).
  // reduce over j within block, one atomicAdd per (n, block). 8 adders/address.
  for (int ni = 0; ni < 4; ni++) {
    float v = 0.0f;
    for (int mi = 0; mi < 4; mi++) {
      const int jb = aRow0 + waveM * 64 + mi * 16 + quad * 4;
      union { float4_t v4; float f[4]; } u;
      u.v4 = acc[mi][ni];
      for (int r = 0; r < 4; r++)
        v += Wmta[jb + r] * tanh_fast(u.f[r]);
    }
    v += __shfl_xor(v, 16);
    v += __shfl_xor(v, 32);
    if (quad == 0) {
      const int n = bRow0 + waveN * 64 + ni * 16 + col;
      atomicAdd(&s[n], v);
    }
  }
}

// ---- softmax stats, stage 1: 32 blocks x 256 threads, online (m,p) partials
__global__ __launch_bounds__(256) void k_stats1(const float* __restrict__ s,
                                                float* __restrict__ pstat) {
  const int tid = threadIdx.x;
  const int lane = tid & 63;
  const int wvi = tid >> 6;
  __shared__ float smM[4], smP[4];
  const float4* s4 = (const float4*)s;

  float4 v = s4[blockIdx.x * 256 + tid];
  float m = fmaxf(fmaxf(v.x, v.y), fmaxf(v.z, v.w));
  float p = __expf(v.x - m) + __expf(v.y - m) + __expf(v.z - m) + __expf(v.w - m);
  for (int o = 32; o > 0; o >>= 1) {
    float om = __shfl_xor(m, o);
    float op = __shfl_xor(p, o);
    float nm = fmaxf(m, om);
    p = p * __expf(m - nm) + op * __expf(om - nm);
    m = nm;
  }
  if (lane == 0) { smM[wvi] = m; smP[wvi] = p; }
  __syncthreads();
  if (tid == 0) {
    float gm = fmaxf(fmaxf(smM[0], smM[1]), fmaxf(smM[2], smM[3]));
    float sum = 0.f;
    for (int w = 0; w < 4; w++) sum += smP[w] * __expf(smM[w] - gm);
    pstat[blockIdx.x * 2]     = gm;
    pstat[blockIdx.x * 2 + 1] = sum;
  }
}

// ---- softmax stats, stage 2: merge 32 partials ----
__global__ __launch_bounds__(64) void k_stats2(const float* __restrict__ pstat,
                                               float* __restrict__ stats) {
  const int tid = threadIdx.x;  // one wave
  float m = -3.4e38f, p = 0.0f;
  if (tid < 32) { m = pstat[tid * 2]; p = pstat[tid * 2 + 1]; }
  for (int o = 32; o > 0; o >>= 1) {
    float om = __shfl_xor(m, o);
    float op = __shfl_xor(p, o);
    float nm = fmaxf(m, om);
    p = p * __expf(m - nm) + op * __expf(om - nm);
    m = nm;
  }
  if (tid == 0) { stats[0] = m; stats[1] = 1.0f / p; }
}

// ---- pooling partials from fp32 V: part[b][d] = sum_{n in blk} w[n]*V[n,d]
// softmax is near-one-hot: w<1e-12 rows are skipped (block-uniform branch),
// so V is touched for only ~tens of rows total.
__global__ __launch_bounds__(256) void k_pool(const float* __restrict__ V,
                                              const float* __restrict__ s,
                                              const float* __restrict__ stats,
                                              float* __restrict__ part) {
  const int tid = threadIdx.x;
  const float mx = stats[0], inv = stats[1];
  const int n0 = blockIdx.x * 128;
  float acc[8] = {0.f, 0.f, 0.f, 0.f, 0.f, 0.f, 0.f, 0.f};
  for (int r = 0; r < 128; ++r) {
    const int n = n0 + r;
    const float w = __expf(s[n] - mx) * inv;
    if (w > 1e-12f) {  // skipped terms contribute < 1.6e-7 total
      const float4* vp = (const float4*)&V[(size_t)n * DIM + tid * 8];
      float4 va = vp[0], vb = vp[1];
      acc[0] += w * va.x; acc[1] += w * va.y; acc[2] += w * va.z; acc[3] += w * va.w;
      acc[4] += w * vb.x; acc[5] += w * vb.y; acc[6] += w * vb.z; acc[7] += w * vb.w;
    }
  }
  float* dst = &part[(size_t)blockIdx.x * DIM + tid * 8];
  *(float4*)(dst + 0) = make_float4(acc[0], acc[1], acc[2], acc[3]);
  *(float4*)(dst + 4) = make_float4(acc[4], acc[5], acc[6], acc[7]);
}

// ---- reduce partials + final linear fused:
// t[d] = sum_b part[b][d]; out[c] += W[c,d]*t[d] (atomic across 8 blocks)
__global__ __launch_bounds__(256) void k_reduce_final(const float* __restrict__ part,
                                                      const float* __restrict__ W,
                                                      float* __restrict__ out) {
  const int d = blockIdx.x * 256 + threadIdx.x;
  float t = 0.f;
  for (int bb = 0; bb < 256; ++bb) t += part[(size_t)bb * DIM + d];

  float pc[NCLS];
#pragma unroll
  for (int c = 0; c < NCLS; ++c) pc[c] = W[(size_t)c * DIM + d] * t;

  __shared__ float sred[4][NCLS];
  const int lane = threadIdx.x & 63;
  const int wvi = threadIdx.x >> 6;
#pragma unroll
  for (int c = 0; c < NCLS; ++c)
    for (int o = 32; o > 0; o >>= 1) pc[c] += __shfl_xor(pc[c], o);
  if (lane == 0)
    for (int c = 0; c < NCLS; ++c) sred[wvi][c] = pc[c];
  __syncthreads();
  if (threadIdx.x < NCLS) {
    float v = sred[0][threadIdx.x] + sred[1][threadIdx.x] +
              sred[2][threadIdx.x] + sred[3][threadIdx.x];
    atomicAdd(&out[threadIdx.x], v);
  }
}

extern "C" void kernel_launch(void* const* d_in, const int* in_sizes, int n_in,
                              void* d_out, int out_size, void* d_ws, size_t ws_size,
                              hipStream_t stream) {
  const float* Vp   = (const float*)d_in[0];  // [N, 2048]
  const float* Ut   = (const float*)d_in[1];  // [512, 2048]
  const float* Wmta = (const float*)d_in[2];  // [1, 512]
  const float* W    = (const float*)d_in[3];  // [4, 2048]
  float* out = (float*)d_out;

  char* ws = (char*)d_ws;
  _Float16* Uhi  = (_Float16*)(ws + OFF_UHI);
  float*    sBuf = (float*)(ws + OFF_S);
  float*    stat = (float*)(ws + OFF_STAT);
  float*    pstat= (float*)(ws + OFF_PSTAT);
  float*    partB= (float*)(ws + OFF_PART);

  hipMemsetAsync(sBuf, 0, (size_t)N_INST * 4, stream);
  hipMemsetAsync(out, 0, (size_t)NCLS * 4, stream);

  k_cvt<<<(DP * DIM / 8) / 256, 256, 0, stream>>>((const float4*)Ut, (half8_t*)Uhi);
  k_score_gemm<<<(DP / 128) * (N_INST / 128), 256, 0, stream>>>(Uhi, Vp, Wmta, sBuf);
  k_stats1<<<32, 256, 0, stream>>>(sBuf, pstat);
  k_stats2<<<1, 64, 0, stream>>>(pstat, stat);
  k_pool<<<N_INST / 128, 256, 0, stream>>>(Vp, sBuf, stat, partB);
  k_reduce_final<<<DIM / 256, 256, 0, stream>>>(partB, W, out);
}